// Round 7
// baseline (249.752 us; speedup 1.0000x reference)
//
#include <hip/hip_runtime.h>

// out[b,s] = cumsum_s( softplus(beta * c[b,s]) / beta ), fp32, B=4096, S=8192.
//
// R8 design: TWO-PASS, both kernels as FULLY-RESIDENT ROLLED GRID-STRIDE loops.
//   Post-mortem R7: dur_us-offset analysis gives K1+K2 ~= 94us; K2 (full
//   268MB read+write pass) ~65-75, K1 (pure read reduce) ~20-30 -> pure-read
//   streams fine; the mixed kernel lags. R6's VGPR=52 proved held buffers
//   don't help either. Remaining invariant of ALL slow variants: one-shot
//   short-lived waves (implicit vmcnt(0) store-drain at s_endpgm per 1024
//   elems + block turnover) and/or fully-unrolled bodies that defeat the
//   loop software-pipeliner. The 6.7 TB/s kernels in this trace (fill, copy
//   ubench) are rolled grid-stride loops in persistent waves.
//   - 2048 blocks x 256 thr = exactly 8 blocks/CU: whole grid resident,
//     zero turnover, teardown drain amortized over 4 chunk-iterations.
//   - Rolled loop, independent iterations -> compiler pipelines next loads
//     over current butterfly/scan/stores.
//   - __launch_bounds__(256,8): VGPR<=64 so 8 waves/SIMD actually fit.
//   - K1: per-chunk softplus sums -> ws. K2: chunk prefix (masked sum of 8
//     cached row sums) + in-chunk scan -> out. Bodies as in R7.
//   - ws: 32768 floats = 128 KB.

#define ROW_S   8192
#define CHUNK   1024                  // elems per wave-chunk
#define NCH     (ROW_S / CHUNK)       // 8 chunks per row
#define WPB     4                     // waves per block (256 thr)
#define BLOCK_T (WPB * 64)
#define NBLOCKS 2048                  // 8 blocks/CU x 256 CU: fully resident

typedef float f32x4 __attribute__((ext_vector_type(4)));

__device__ __forceinline__ float softplus_step(float c, float beta, float inv_beta) {
    float tb = beta * c;
    float a  = fabsf(tb);
    float e  = __expf(-a);             // in (0,1], no overflow
    float l  = __logf(1.0f + e);       // log1p(exp(-|t|))
    return (fmaxf(tb, 0.0f) + l) * inv_beta;
}

// ---- K1: per-chunk softplus sums -> sums[chunk], grid-stride ----
__global__ __launch_bounds__(BLOCK_T, 8) void chunk_sum_kernel(
    const float* __restrict__ c,
    const float* __restrict__ beta_p,
    float* __restrict__ sums,
    int nchunks)
{
    const int lane    = threadIdx.x & 63;
    const int wave    = threadIdx.x >> 6;
    const int wslot   = blockIdx.x * WPB + wave;
    const int wstride = gridDim.x * WPB;

    const float beta     = beta_p[0];
    const float inv_beta = 1.0f / beta;

    for (int g = wslot; g < nchunks; g += wstride) {
        const f32x4* __restrict__ in4 = (const f32x4*)c + (size_t)g * (CHUNK / 4);

        f32x4 v[4];
        #pragma unroll
        for (int j = 0; j < 4; ++j)
            v[j] = in4[j * 64 + lane];              // coalesced 1KB/instr

        // 4 independent partial sums (short chains), then combine
        float s0 = 0.f, s1 = 0.f, s2 = 0.f, s3 = 0.f;
        #pragma unroll
        for (int j = 0; j < 4; ++j) {
            s0 += softplus_step(v[j].x, beta, inv_beta);
            s1 += softplus_step(v[j].y, beta, inv_beta);
            s2 += softplus_step(v[j].z, beta, inv_beta);
            s3 += softplus_step(v[j].w, beta, inv_beta);
        }
        float s = (s0 + s1) + (s2 + s3);

        #pragma unroll
        for (int d = 1; d < 64; d <<= 1)
            s += __shfl_xor(s, d, 64);              // butterfly total

        if (lane == 0) sums[g] = s;
    }
}

// ---- K2: chunk prefix + in-chunk scan -> out, grid-stride ----
__global__ __launch_bounds__(BLOCK_T, 8) void scan_apply_kernel(
    const float* __restrict__ c,
    const float* __restrict__ beta_p,
    const float* __restrict__ sums,
    float* __restrict__ out,
    int nchunks)
{
    const int lane    = threadIdx.x & 63;
    const int wave    = threadIdx.x >> 6;
    const int wslot   = blockIdx.x * WPB + wave;
    const int wstride = gridDim.x * WPB;

    const float beta     = beta_p[0];
    const float inv_beta = 1.0f / beta;

    for (int g = wslot; g < nchunks; g += wstride) {
        const int jch     = g & (NCH - 1);          // chunk index within row
        const int rowbase = g & ~(NCH - 1);         // row's first chunk id

        // chunk prefix: masked sum of this row's 8 sums (32B, L2-hot)
        float pre0 = 0.0f;
        #pragma unroll
        for (int k = 0; k < NCH; ++k) {
            float w = sums[rowbase + k];
            if (k < jch) pre0 += w;
        }

        const f32x4* __restrict__ in4  = (const f32x4*)c   + (size_t)g * (CHUNK / 4);
        f32x4*       __restrict__ out4 = (f32x4*)out       + (size_t)g * (CHUNK / 4);

        f32x4 v[4];
        #pragma unroll
        for (int j = 0; j < 4; ++j)
            v[j] = in4[j * 64 + lane];              // L3-warm re-read

        // softplus + in-f4 inclusive scan
        f32x4 r[4];
        float s[4];
        #pragma unroll
        for (int j = 0; j < 4; ++j) {
            float a = softplus_step(v[j].x, beta, inv_beta);
            float b = softplus_step(v[j].y, beta, inv_beta);
            float d = softplus_step(v[j].z, beta, inv_beta);
            float e = softplus_step(v[j].w, beta, inv_beta);
            r[j].x = a;
            r[j].y = a + b;
            r[j].z = r[j].y + d;
            r[j].w = r[j].z + e;
            s[j]   = r[j].w;
        }

        // 4 independent wave-inclusive shuffle scans of group sums
        float xs[4], G[4];
        #pragma unroll
        for (int j = 0; j < 4; ++j) {
            float x = s[j];
            #pragma unroll
            for (int d = 1; d < 64; d <<= 1) {
                float y = __shfl_up(x, d, 64);
                if (lane >= d) x += y;
            }
            xs[j] = x;
            G[j]  = __shfl(x, 63, 64);              // group total
        }

        // combine + coalesced stores
        float pre = pre0;
        #pragma unroll
        for (int j = 0; j < 4; ++j) {
            const float off = pre + (xs[j] - s[j]); // exclusive prefix for lane
            pre += G[j];
            f32x4 o;
            o.x = r[j].x + off;
            o.y = r[j].y + off;
            o.z = r[j].z + off;
            o.w = r[j].w + off;
            out4[j * 64 + lane] = o;
        }
    }
}

extern "C" void kernel_launch(void* const* d_in, const int* in_sizes, int n_in,
                              void* d_out, int out_size, void* d_ws, size_t ws_size,
                              hipStream_t stream) {
    const float* c      = (const float*)d_in[0];
    const float* beta_p = (const float*)d_in[1];
    float*       out    = (float*)d_out;

    const int B       = in_sizes[0] / ROW_S;        // 4096 rows
    const int nchunks = B * NCH;                    // 32768 chunks

    int grid = NBLOCKS;
    const int needed = (nchunks + WPB - 1) / WPB;
    if (needed < grid) grid = needed;

    float* sums = (float*)d_ws;                     // 128 KB of workspace

    chunk_sum_kernel<<<dim3(grid), dim3(BLOCK_T), 0, stream>>>(
        c, beta_p, sums, nchunks);
    scan_apply_kernel<<<dim3(grid), dim3(BLOCK_T), 0, stream>>>(
        c, beta_p, sums, out, nchunks);
}